// Round 2
// baseline (11765.983 us; speedup 1.0000x reference)
//
#include <hip/hip_runtime.h>

// Problem constants
#define NB    16
#define NT    3
#define NCTX  2048
#define NLAT  512
#define DIMV  512
#define HALFD 256
#define NFEAT 51
#define NBT   48
#define MROWS 24576    // NBT*NLAT
#define GRP   8        // bt per context group
#define NGRP  6
#define GROWS 16384    // GRP*NCTX

typedef unsigned short bfu;   // bf16 storage as raw bits

__device__ __forceinline__ float bf2f(bfu u){ return __uint_as_float(((unsigned int)u) << 16); }
__device__ __forceinline__ bfu f2bf(float f){
  unsigned int u = __float_as_uint(f);
  u += 0x7FFFu + ((u >> 16) & 1u);          // RNE
  return (bfu)(u >> 16);
}
__device__ __forceinline__ float4 load4(const float* p){ return *(const float4*)p; }
__device__ __forceinline__ float4 load4(const bfu* p){
  ushort4 u = *(const ushort4*)p;
  return make_float4(bf2f(u.x), bf2f(u.y), bf2f(u.z), bf2f(u.w));
}
__device__ __forceinline__ float loadE(const float* p){ return *p; }
__device__ __forceinline__ float loadE(const bfu* p){ return bf2f(*p); }
__device__ __forceinline__ void storeE(float* p, float v){ *p = v; }
__device__ __forceinline__ void storeE(bfu* p, float v){ *p = f2bf(v); }

// ---------------------------------------------------------------------------
// FPS: 16 blocks, exact fp32 match with numpy (no FMA contraction, sum order
// ((dx2+dy2)+dz2), first-occurrence argmax).
// ---------------------------------------------------------------------------
__global__ __launch_bounds__(256) void fps_kernel(const float* __restrict__ pc,
                                                  int* __restrict__ idx_out){
  __shared__ float px[NCTX], py[NCTX], pz[NCTX], dist[NCTX];
  __shared__ float rv[4];
  __shared__ int   ri[4];
  __shared__ int   lastS;
  const int b = blockIdx.x, tid = threadIdx.x;
  const float* src = pc + (size_t)b * (NT * NCTX * 3);
  for (int i = tid; i < NCTX; i += 256){
    px[i] = src[i*3+0]; py[i] = src[i*3+1]; pz[i] = src[i*3+2];
    dist[i] = 1e10f;
  }
  if (tid == 0) idx_out[b * NLAT] = 0;
  __syncthreads();
  int last = 0;
  const int lane = tid & 63, wv = tid >> 6;
  for (int step = 1; step < NLAT; ++step){
    const float lx = px[last], ly = py[last], lz = pz[last];
    float bv = -1.0f; int bi = NCTX;
    for (int i = tid; i < NCTX; i += 256){
      const float dx = __fsub_rn(px[i], lx);
      const float dy = __fsub_rn(py[i], ly);
      const float dz = __fsub_rn(pz[i], lz);
      const float d = __fadd_rn(__fadd_rn(__fmul_rn(dx,dx), __fmul_rn(dy,dy)),
                                __fmul_rn(dz,dz));
      const float nd = fminf(dist[i], d);
      dist[i] = nd;
      if (nd > bv){ bv = nd; bi = i; }
    }
    for (int off = 32; off; off >>= 1){
      const float ov = __shfl_down(bv, off, 64);
      const int   oi = __shfl_down(bi, off, 64);
      if (ov > bv || (ov == bv && oi < bi)){ bv = ov; bi = oi; }
    }
    if (lane == 0){ rv[wv] = bv; ri[wv] = bi; }
    __syncthreads();
    if (tid == 0){
      float bbv = rv[0]; int bbi = ri[0];
      for (int w = 1; w < 4; ++w)
        if (rv[w] > bbv || (rv[w] == bbv && ri[w] < bbi)){ bbv = rv[w]; bbi = ri[w]; }
      lastS = bbi;
      idx_out[b * NLAT + step] = bbi;
    }
    __syncthreads();
    last = lastS;
  }
}

// ---------------------------------------------------------------------------
// Fused (gather) + point_embed x2 + layernorm. bf16 outputs.
// 16 points per block.
// ---------------------------------------------------------------------------
template<bool GATHER, bool WRITE_EMB>
__global__ __launch_bounds__(256) void embed_kernel(
    const float* __restrict__ pc, const float* __restrict__ pc2,
    const int* __restrict__ idx,
    const float* __restrict__ basis, const float* __restrict__ pe_w,
    const float* __restrict__ pe_b,
    const float* __restrict__ ln_g, const float* __restrict__ ln_b,
    bfu* __restrict__ emb, bfu* __restrict__ lnout, int nppbt)
{
  __shared__ float feat[2][16][NFEAT + 1];
  __shared__ float outb[16][DIMV];
  const int tid = threadIdx.x;
  const int p0 = blockIdx.x << 4;

  if (tid < 32){
    const int s = tid >> 4, p = tid & 15;
    const int gp = p0 + p;
    const int bt = gp / nppbt;
    const int n  = gp - bt * nppbt;
    const int bb = bt / NT;
    const int srcn = GATHER ? idx[bb * NLAT + n] : n;
    const float* sp = (s ? pc2 : pc) + ((size_t)bt * NCTX + srcn) * 3;
    const float x0 = sp[0], x1 = sp[1], x2 = sp[2];
    #pragma unroll
    for (int e = 0; e < 24; ++e){
      const float pr = __fadd_rn(__fadd_rn(__fmul_rn(x0, basis[e]),
                                           __fmul_rn(x1, basis[24 + e])),
                                 __fmul_rn(x2, basis[48 + e]));
      feat[s][p][e]      = sinf(pr);
      feat[s][p][24 + e] = cosf(pr);
    }
    feat[s][p][48] = x0; feat[s][p][49] = x1; feat[s][p][50] = x2;
  }
  __syncthreads();

  {
    float w[NFEAT];
    #pragma unroll
    for (int k = 0; k < NFEAT; ++k) w[k] = pe_w[k * HALFD + tid];
    const float bv = pe_b[tid];
    #pragma unroll
    for (int half = 0; half < 2; ++half){
      for (int p = 0; p < 16; ++p){
        float acc = bv;
        #pragma unroll
        for (int k = 0; k < NFEAT; ++k) acc = fmaf(feat[half][p][k], w[k], acc);
        outb[p][half * HALFD + tid] = acc;
      }
    }
  }
  __syncthreads();

  const int lane = tid & 63, wv = tid >> 6;
  for (int pp = 0; pp < 4; ++pp){
    const int p = (wv << 2) + pp;
    const size_t gp = (size_t)p0 + p;
    float x[8];
    #pragma unroll
    for (int j = 0; j < 8; ++j) x[j] = outb[p][lane + (j << 6)];
    float s = 0.f;
    #pragma unroll
    for (int j = 0; j < 8; ++j) s += x[j];
    for (int o = 32; o; o >>= 1) s += __shfl_xor(s, o, 64);
    const float m = s * (1.0f / 512.0f);
    float s2 = 0.f;
    #pragma unroll
    for (int j = 0; j < 8; ++j){ const float d = x[j] - m; s2 = fmaf(d, d, s2); }
    for (int o = 32; o; o >>= 1) s2 += __shfl_xor(s2, o, 64);
    const float inv = 1.0f / sqrtf(s2 * (1.0f / 512.0f) + 1e-5f);
    #pragma unroll
    for (int j = 0; j < 8; ++j){
      const int c = lane + (j << 6);
      const float r = (x[j] - m) * inv * ln_g[c] + ln_b[c];
      const size_t o2 = gp * DIMV + c;
      if (WRITE_EMB) emb[o2] = f2bf(x[j]);
      lnout[o2] = f2bf(r);
    }
  }
}

// ---------------------------------------------------------------------------
// Tiled GEMM: 64x64 tile, BK=16, 256 threads, 4x4 per thread.
// ---------------------------------------------------------------------------
#define EPI_NONE     0
#define EPI_SPLIT    1
#define EPI_BIAS_RES 2

template<typename TA, typename TC, typename TR, int EPI>
__global__ __launch_bounds__(256) void gemm_kernel(
    const TA* __restrict__ A, const float* __restrict__ B,
    TC* __restrict__ C, TC* __restrict__ C2,
    const float* __restrict__ bias, const TR* __restrict__ res,
    int M, int N, int K, int lda, int ldb, int ldc)
{
  const int m0 = blockIdx.y * 64;
  const int n0 = blockIdx.x * 64;
  const int tid = threadIdx.x;
  const int tx = tid & 15, ty = tid >> 4;

  __shared__ float As[16][68];
  __shared__ float Bs[16][68];

  float acc[4][4] = {};

  const int arow = tid >> 2, akq = (tid & 3) << 2;
  const int brow = tid >> 4, bc = (tid & 15) << 2;
  for (int k0 = 0; k0 < K; k0 += 16){
    {
      const float4 av = load4(A + (size_t)(m0 + arow) * lda + k0 + akq);
      As[akq+0][arow] = av.x; As[akq+1][arow] = av.y;
      As[akq+2][arow] = av.z; As[akq+3][arow] = av.w;
    }
    {
      const float4 bv = load4(B + (size_t)(k0 + brow) * ldb + n0 + bc);
      *(float4*)&Bs[brow][bc] = bv;
    }
    __syncthreads();
    #pragma unroll
    for (int kk = 0; kk < 16; ++kk){
      const float4 a4 = *(const float4*)&As[kk][ty << 2];
      const float4 b4 = *(const float4*)&Bs[kk][tx << 2];
      const float a[4] = {a4.x, a4.y, a4.z, a4.w};
      const float b[4] = {b4.x, b4.y, b4.z, b4.w};
      #pragma unroll
      for (int i = 0; i < 4; ++i)
        #pragma unroll
        for (int j = 0; j < 4; ++j)
          acc[i][j] = fmaf(a[i], b[j], acc[i][j]);
    }
    __syncthreads();
  }

  #pragma unroll
  for (int i = 0; i < 4; ++i){
    const int cm = m0 + (ty << 2) + i;
    #pragma unroll
    for (int j = 0; j < 4; ++j){
      const int cn = n0 + (tx << 2) + j;
      float v = acc[i][j];
      if (EPI == EPI_BIAS_RES) v = v + bias[cn] + loadE(&res[(size_t)cm * ldc + cn]);
      if (EPI == EPI_SPLIT){
        const int half = N >> 1;
        if (cn < half) storeE(&C [(size_t)cm * half + cn],          v);
        else           storeE(&C2[(size_t)cm * half + (cn - half)], v);
      } else {
        storeE(&C[(size_t)cm * ldc + cn], v);
      }
    }
  }
}

// ---------------------------------------------------------------------------
// Fused MLP1 + GeLU: act[m,n] = (lnx@w1[:,n]+b1[n]) * gelu(lnx@w1[:,n+2048]+b1[n+2048])
// 64x64 output tile of the 2048-wide act. A bf16, w1 fp32.
// ---------------------------------------------------------------------------
__global__ __launch_bounds__(256) void mlp1_kernel(
    const bfu* __restrict__ A, const float* __restrict__ B,
    const float* __restrict__ b1, bfu* __restrict__ act)
{
  const int m0 = blockIdx.y * 64;
  const int n0 = blockIdx.x * 64;
  const int tid = threadIdx.x;
  const int tx = tid & 15, ty = tid >> 4;

  __shared__ float As[16][68];
  __shared__ float Ba[16][68];
  __shared__ float Bg[16][68];

  float acca[4][4] = {}, accg[4][4] = {};

  const int arow = tid >> 2, akq = (tid & 3) << 2;
  const int brow = tid >> 4, bc = (tid & 15) << 2;
  for (int k0 = 0; k0 < 512; k0 += 16){
    {
      const float4 av = load4(A + (size_t)(m0 + arow) * 512 + k0 + akq);
      As[akq+0][arow] = av.x; As[akq+1][arow] = av.y;
      As[akq+2][arow] = av.z; As[akq+3][arow] = av.w;
    }
    {
      const float* bp = B + (size_t)(k0 + brow) * 4096 + n0 + bc;
      *(float4*)&Ba[brow][bc] = load4(bp);
      *(float4*)&Bg[brow][bc] = load4(bp + 2048);
    }
    __syncthreads();
    #pragma unroll
    for (int kk = 0; kk < 16; ++kk){
      const float4 a4 = *(const float4*)&As[kk][ty << 2];
      const float4 ba = *(const float4*)&Ba[kk][tx << 2];
      const float4 bg = *(const float4*)&Bg[kk][tx << 2];
      const float a[4] = {a4.x, a4.y, a4.z, a4.w};
      const float vba[4] = {ba.x, ba.y, ba.z, ba.w};
      const float vbg[4] = {bg.x, bg.y, bg.z, bg.w};
      #pragma unroll
      for (int i = 0; i < 4; ++i)
        #pragma unroll
        for (int j = 0; j < 4; ++j){
          acca[i][j] = fmaf(a[i], vba[j], acca[i][j]);
          accg[i][j] = fmaf(a[i], vbg[j], accg[i][j]);
        }
    }
    __syncthreads();
  }

  #pragma unroll
  for (int i = 0; i < 4; ++i){
    const int cm = m0 + (ty << 2) + i;
    #pragma unroll
    for (int j = 0; j < 4; ++j){
      const int cn = n0 + (tx << 2) + j;
      const float a = acca[i][j] + b1[cn];
      const float g = accg[i][j] + b1[cn + 2048];
      const float ge = g * 0.5f * (1.0f + erff(g * 0.70710678118654752f));
      act[(size_t)cm * 2048 + cn] = f2bf(a * ge);
    }
  }
}

// ---------------------------------------------------------------------------
// Flash attention for one group of GRP bt. Q tile = 16 rows, ctx tile = 16.
// grid (32 qblocks, GRP), 256 threads.
// ---------------------------------------------------------------------------
#define QT 16
#define CT 16
__global__ __launch_bounds__(256) void attn_kernel(
    const bfu* __restrict__ q, const bfu* __restrict__ kg,
    const bfu* __restrict__ vg, bfu* __restrict__ o, int bt0)
{
  __shared__ bfu q_s[QT][516];
  __shared__ bfu k_s[CT][516];
  __shared__ bfu v_s[CT][516];
  __shared__ float P_s[QT][CT];
  __shared__ float m_s[QT], l_s[QT], al_s[QT];

  const int tid = threadIdx.x;
  const int btl = blockIdx.y;
  const size_t qrow0 = ((size_t)(bt0 + btl) * NLAT) + (size_t)blockIdx.x * QT;
  const bfu* kb = kg + (size_t)btl * NCTX * DIMV;
  const bfu* vb = vg + (size_t)btl * NCTX * DIMV;

  {
    const int r = tid >> 4, h0 = (tid & 15) * 32;
    const bfu* src = q + (qrow0 + r) * DIMV + h0;
    #pragma unroll
    for (int u = 0; u < 8; ++u)
      *(ushort4*)&q_s[r][h0 + u*4] = *(const ushort4*)(src + u*4);
  }
  if (tid < QT){ m_s[tid] = -1e30f; l_s[tid] = 0.f; }

  float O[4][8] = {};
  const int lane = tid & 63, wv = tid >> 6;
  const int sr = tid >> 4, sc = tid & 15;
  __syncthreads();

  for (int t0 = 0; t0 < NCTX; t0 += CT){
    {
      const int r = tid >> 4, h0 = (tid & 15) * 32;
      const bfu* ks = kb + (size_t)(t0 + r) * DIMV + h0;
      const bfu* vs = vb + (size_t)(t0 + r) * DIMV + h0;
      #pragma unroll
      for (int u = 0; u < 8; ++u){
        *(ushort4*)&k_s[r][h0 + u*4] = *(const ushort4*)(ks + u*4);
        *(ushort4*)&v_s[r][h0 + u*4] = *(const ushort4*)(vs + u*4);
      }
    }
    __syncthreads();

    // S[sr][sc] = q_row . k_row * scale
    float acc = 0.f;
    for (int k = 0; k < DIMV; k += 4){
      const ushort4 qa = *(const ushort4*)&q_s[sr][k];
      const ushort4 ka = *(const ushort4*)&k_s[sc][k];
      acc = fmaf(bf2f(qa.x), bf2f(ka.x), acc);
      acc = fmaf(bf2f(qa.y), bf2f(ka.y), acc);
      acc = fmaf(bf2f(qa.z), bf2f(ka.z), acc);
      acc = fmaf(bf2f(qa.w), bf2f(ka.w), acc);
    }
    acc *= 0.044194173824159216f;

    float mx = acc;
    for (int off2 = 8; off2; off2 >>= 1) mx = fmaxf(mx, __shfl_xor(mx, off2, 64));
    const float m_old = m_s[sr];
    const float m_new = fmaxf(m_old, mx);
    const float p = __expf(acc - m_new);
    float ps = p;
    for (int off2 = 8; off2; off2 >>= 1) ps += __shfl_xor(ps, off2, 64);
    const float alpha = __expf(m_old - m_new);
    if (sc == 0){ m_s[sr] = m_new; l_s[sr] = fmaf(l_s[sr], alpha, ps); al_s[sr] = alpha; }
    P_s[sr][sc] = p;
    __syncthreads();

    #pragma unroll
    for (int rr = 0; rr < 4; ++rr){
      const float al = al_s[wv*4 + rr];
      #pragma unroll
      for (int jj = 0; jj < 8; ++jj) O[rr][jj] *= al;
    }
    for (int j = 0; j < CT; ++j){
      float pv[4];
      #pragma unroll
      for (int rr = 0; rr < 4; ++rr) pv[rr] = P_s[wv*4 + rr][j];
      #pragma unroll
      for (int jj = 0; jj < 8; ++jj){
        const float vvl = bf2f(v_s[j][lane + 64*jj]);
        #pragma unroll
        for (int rr = 0; rr < 4; ++rr) O[rr][jj] = fmaf(pv[rr], vvl, O[rr][jj]);
      }
    }
    __syncthreads();
  }

  #pragma unroll
  for (int rr = 0; rr < 4; ++rr){
    const int r = wv*4 + rr;
    const float inv = 1.0f / l_s[r];
    bfu* orow = o + (qrow0 + r) * DIMV;
    #pragma unroll
    for (int jj = 0; jj < 8; ++jj) orow[lane + 64*jj] = f2bf(O[rr][jj] * inv);
  }
}

// ---------------------------------------------------------------------------
// LayerNorm rows of 512 fp32 -> bf16.
// ---------------------------------------------------------------------------
__global__ __launch_bounds__(256) void ln_kernel(const float* __restrict__ in,
                                                 const float* __restrict__ g,
                                                 const float* __restrict__ b,
                                                 bfu* __restrict__ out){
  const int tid = threadIdx.x, lane = tid & 63, wv = tid >> 6;
  const size_t row = (size_t)blockIdx.x * 4 + wv;
  const float* rp = in + row * DIMV;
  float x[8];
  #pragma unroll
  for (int j = 0; j < 8; ++j) x[j] = rp[lane + (j << 6)];
  float s = 0.f;
  #pragma unroll
  for (int j = 0; j < 8; ++j) s += x[j];
  for (int o = 32; o; o >>= 1) s += __shfl_xor(s, o, 64);
  const float m = s * (1.0f / 512.0f);
  float s2 = 0.f;
  #pragma unroll
  for (int j = 0; j < 8; ++j){ const float d = x[j] - m; s2 = fmaf(d, d, s2); }
  for (int o = 32; o; o >>= 1) s2 += __shfl_xor(s2, o, 64);
  const float inv = 1.0f / sqrtf(s2 * (1.0f / 512.0f) + 1e-5f);
  bfu* op = out + row * DIMV;
  #pragma unroll
  for (int j = 0; j < 8; ++j){
    const int c = lane + (j << 6);
    op[c] = f2bf((x[j] - m) * inv * g[c] + b[c]);
  }
}

// ---------------------------------------------------------------------------
// Workspace layout (peak 125,861,888 B ~= 120 MiB):
//   OFF_IDX = 0          idx (32 KB)
//   OFF_A   = 32768      emb_s   bf16 24576x512 (25,165,824)   \
//   OFF_B   = 25198592   q_in -> attnout bf16   (25,165,824)    | act (bf16
//   OFF_E   = 50364416   c_in_grp bf16 16384x512 (16,777,216)   | 24576x2048)
//   OFF_D   = 67141632   kv group bf16 (33,554,432)            /  aliases A..D
//   OFF_C   = 100696064  q -> lnx bf16 (25,165,824)
// ---------------------------------------------------------------------------
extern "C" void kernel_launch(void* const* d_in, const int* in_sizes, int n_in,
                              void* d_out, int out_size, void* d_ws, size_t ws_size,
                              hipStream_t stream)
{
  (void)in_sizes; (void)n_in; (void)out_size;
  if (ws_size < 125861888ull) return;   // clean failure instead of OOB crash

  const float* pc    = (const float*)d_in[0];
  const float* pc2   = (const float*)d_in[1];
  const float* basis = (const float*)d_in[2];
  const float* pe_w  = (const float*)d_in[3];
  const float* pe_b  = (const float*)d_in[4];
  const float* lnq_g = (const float*)d_in[5];
  const float* lnq_b = (const float*)d_in[6];
  const float* lnc_g = (const float*)d_in[7];
  const float* lnc_b = (const float*)d_in[8];
  const float* wq    = (const float*)d_in[9];
  const float* wkv   = (const float*)d_in[10];
  const float* wo    = (const float*)d_in[11];
  const float* bo    = (const float*)d_in[12];
  const float* lnf_g = (const float*)d_in[13];
  const float* lnf_b = (const float*)d_in[14];
  const float* w1    = (const float*)d_in[15];
  const float* b1    = (const float*)d_in[16];
  const float* w2    = (const float*)d_in[17];
  const float* b2    = (const float*)d_in[18];
  float* xout = (float*)d_out;

  char* ws = (char*)d_ws;
  int* idxb    = (int*)(ws);
  bfu* emb_s   = (bfu*)(ws + 32768);
  bfu* q_in    = (bfu*)(ws + 25198592);
  bfu* c_grp   = (bfu*)(ws + 50364416);
  bfu* k_grp   = (bfu*)(ws + 67141632);
  bfu* v_grp   = (bfu*)(ws + 83918848);
  bfu* qbuf    = (bfu*)(ws + 100696064);
  bfu* attnout = q_in;                   // after q GEMM consumed q_in
  bfu* lnx     = qbuf;                   // after attention consumed q
  bfu* actb    = emb_s;                  // spans A..D after wo GEMM

  // 1. FPS
  fps_kernel<<<NB, 256, 0, stream>>>(pc, idxb);

  // 2. latent embed -> emb_s (raw) + q_in (LN'd), bf16
  embed_kernel<true, true><<<MROWS/16, 256, 0, stream>>>(
      pc, pc2, idxb, basis, pe_w, pe_b, lnq_g, lnq_b, emb_s, q_in, NLAT);

  // 3. q = q_in @ wq (bf16)
  gemm_kernel<bfu, bfu, float, EPI_NONE><<<dim3(8, 384), 256, 0, stream>>>(
      q_in, wq, qbuf, nullptr, nullptr, nullptr, MROWS, 512, 512, 512, 512, 512);

  // 4. per-group: ctx embed -> kv -> flash attention
  for (int g = 0; g < NGRP; ++g){
    const int bt0 = g * GRP;
    embed_kernel<false, false><<<GROWS/16, 256, 0, stream>>>(
        pc + (size_t)bt0 * NCTX * 3, pc2 + (size_t)bt0 * NCTX * 3, nullptr,
        basis, pe_w, pe_b, lnc_g, lnc_b, nullptr, c_grp, NCTX);

    gemm_kernel<bfu, bfu, float, EPI_SPLIT><<<dim3(16, 256), 256, 0, stream>>>(
        c_grp, wkv, k_grp, v_grp, nullptr, nullptr,
        GROWS, 1024, 512, 512, 1024, 512);

    attn_kernel<<<dim3(32, GRP), 256, 0, stream>>>(qbuf, k_grp, v_grp, attnout, bt0);
  }

  // 5. x = attnout @ wo + bo + emb_s -> d_out (fp32)
  gemm_kernel<bfu, float, bfu, EPI_BIAS_RES><<<dim3(8, 384), 256, 0, stream>>>(
      attnout, wo, xout, nullptr, bo, emb_s, MROWS, 512, 512, 512, 512, 512);

  // 6. lnx = LN(x)
  ln_kernel<<<MROWS/4, 256, 0, stream>>>(xout, lnf_g, lnf_b, lnx);

  // 7. act = (lnx@w1a + b1a) * gelu(lnx@w1g + b1g), bf16
  mlp1_kernel<<<dim3(32, 384), 256, 0, stream>>>(lnx, w1, b1, actb);

  // 8. x += act @ w2 + b2 (in place on d_out)
  gemm_kernel<bfu, float, float, EPI_BIAS_RES><<<dim3(8, 384), 256, 0, stream>>>(
      actb, w2, xout, nullptr, b2, xout, MROWS, 512, 2048, 2048, 512, 512);
}

// Round 3
// 2909.712 us; speedup vs baseline: 4.0437x; 4.0437x over previous
//
#include <hip/hip_runtime.h>

// Problem constants
#define NB    16
#define NT    3
#define NCTX  2048
#define NLAT  512
#define DIMV  512
#define HALFD 256
#define NFEAT 51
#define NBT   48
#define MROWS 24576    // NBT*NLAT
#define GRP   4        // bt per context group
#define NGRP  12
#define GROWS 8192     // GRP*NCTX

typedef unsigned short bfu;   // bf16 storage as raw bits
typedef short bf16x8 __attribute__((ext_vector_type(8)));   // 8 bf16 = 4 VGPR
typedef float f32x4  __attribute__((ext_vector_type(4)));   // MFMA 16x16 acc

__device__ __forceinline__ float bf2f(bfu u){ return __uint_as_float(((unsigned int)u) << 16); }
__device__ __forceinline__ bfu f2bf(float f){
  unsigned int u = __float_as_uint(f);
  u += 0x7FFFu + ((u >> 16) & 1u);          // RNE
  return (bfu)(u >> 16);
}
__device__ __forceinline__ float loadE(const float* p){ return *p; }
__device__ __forceinline__ float loadE(const bfu* p){ return bf2f(*p); }
__device__ __forceinline__ void storeE(float* p, float v){ *p = v; }
__device__ __forceinline__ void storeE(bfu* p, float v){ *p = f2bf(v); }
__device__ __forceinline__ bfu to_bfu(float f){ return f2bf(f); }
__device__ __forceinline__ bfu to_bfu(bfu u){ return u; }

// ---------------------------------------------------------------------------
// FPS: bit-exact fp32 (no FMA contraction, numpy sum order, first-occurrence
// argmax). One block per batch.
// ---------------------------------------------------------------------------
__global__ __launch_bounds__(256) void fps_kernel(const float* __restrict__ pc,
                                                  int* __restrict__ idx_out){
  __shared__ float px[NCTX], py[NCTX], pz[NCTX], dist[NCTX];
  __shared__ float rv[4];
  __shared__ int   ri[4];
  __shared__ int   lastS;
  const int b = blockIdx.x, tid = threadIdx.x;
  const float* src = pc + (size_t)b * (NT * NCTX * 3);
  for (int i = tid; i < NCTX; i += 256){
    px[i] = src[i*3+0]; py[i] = src[i*3+1]; pz[i] = src[i*3+2];
    dist[i] = 1e10f;
  }
  if (tid == 0) idx_out[b * NLAT] = 0;
  __syncthreads();
  int last = 0;
  const int lane = tid & 63, wv = tid >> 6;
  for (int step = 1; step < NLAT; ++step){
    const float lx = px[last], ly = py[last], lz = pz[last];
    float bv = -1.0f; int bi = NCTX;
    for (int i = tid; i < NCTX; i += 256){
      const float dx = __fsub_rn(px[i], lx);
      const float dy = __fsub_rn(py[i], ly);
      const float dz = __fsub_rn(pz[i], lz);
      const float d = __fadd_rn(__fadd_rn(__fmul_rn(dx,dx), __fmul_rn(dy,dy)),
                                __fmul_rn(dz,dz));
      const float nd = fminf(dist[i], d);
      dist[i] = nd;
      if (nd > bv){ bv = nd; bi = i; }
    }
    for (int off = 32; off; off >>= 1){
      const float ov = __shfl_down(bv, off, 64);
      const int   oi = __shfl_down(bi, off, 64);
      if (ov > bv || (ov == bv && oi < bi)){ bv = ov; bi = oi; }
    }
    if (lane == 0){ rv[wv] = bv; ri[wv] = bi; }
    __syncthreads();
    if (tid == 0){
      float bbv = rv[0]; int bbi = ri[0];
      for (int w = 1; w < 4; ++w)
        if (rv[w] > bbv || (rv[w] == bbv && ri[w] < bbi)){ bbv = rv[w]; bbi = ri[w]; }
      lastS = bbi;
      idx_out[b * NLAT + step] = bbi;
    }
    __syncthreads();
    last = lastS;
  }
}

// ---------------------------------------------------------------------------
// Fused (gather) + point_embed x2 + layernorm -> bf16. 16 points / block.
// ---------------------------------------------------------------------------
template<bool GATHER, bool WRITE_EMB>
__global__ __launch_bounds__(256) void embed_kernel(
    const float* __restrict__ pc, const float* __restrict__ pc2,
    const int* __restrict__ idx,
    const float* __restrict__ basis, const float* __restrict__ pe_w,
    const float* __restrict__ pe_b,
    const float* __restrict__ ln_g, const float* __restrict__ ln_b,
    bfu* __restrict__ emb, bfu* __restrict__ lnout, int nppbt)
{
  __shared__ float feat[2][16][NFEAT + 1];
  __shared__ float outb[16][DIMV];
  const int tid = threadIdx.x;
  const int p0 = blockIdx.x << 4;

  if (tid < 32){
    const int s = tid >> 4, p = tid & 15;
    const int gp = p0 + p;
    const int bt = gp / nppbt;
    const int n  = gp - bt * nppbt;
    const int bb = bt / NT;
    const int srcn = GATHER ? idx[bb * NLAT + n] : n;
    const float* sp = (s ? pc2 : pc) + ((size_t)bt * NCTX + srcn) * 3;
    const float x0 = sp[0], x1 = sp[1], x2 = sp[2];
    #pragma unroll
    for (int e = 0; e < 24; ++e){
      const float pr = __fadd_rn(__fadd_rn(__fmul_rn(x0, basis[e]),
                                           __fmul_rn(x1, basis[24 + e])),
                                 __fmul_rn(x2, basis[48 + e]));
      feat[s][p][e]      = sinf(pr);
      feat[s][p][24 + e] = cosf(pr);
    }
    feat[s][p][48] = x0; feat[s][p][49] = x1; feat[s][p][50] = x2;
  }
  __syncthreads();

  {
    float w[NFEAT];
    #pragma unroll
    for (int k = 0; k < NFEAT; ++k) w[k] = pe_w[k * HALFD + tid];
    const float bv = pe_b[tid];
    #pragma unroll
    for (int half = 0; half < 2; ++half){
      for (int p = 0; p < 16; ++p){
        float acc = bv;
        #pragma unroll
        for (int k = 0; k < NFEAT; ++k) acc = fmaf(feat[half][p][k], w[k], acc);
        outb[p][half * HALFD + tid] = acc;
      }
    }
  }
  __syncthreads();

  const int lane = tid & 63, wv = tid >> 6;
  for (int pp = 0; pp < 4; ++pp){
    const int p = (wv << 2) + pp;
    const size_t gp = (size_t)p0 + p;
    float x[8];
    #pragma unroll
    for (int j = 0; j < 8; ++j) x[j] = outb[p][lane + (j << 6)];
    float s = 0.f;
    #pragma unroll
    for (int j = 0; j < 8; ++j) s += x[j];
    for (int o = 32; o; o >>= 1) s += __shfl_xor(s, o, 64);
    const float m = s * (1.0f / 512.0f);
    float s2 = 0.f;
    #pragma unroll
    for (int j = 0; j < 8; ++j){ const float d = x[j] - m; s2 = fmaf(d, d, s2); }
    for (int o = 32; o; o >>= 1) s2 += __shfl_xor(s2, o, 64);
    const float inv = 1.0f / sqrtf(s2 * (1.0f / 512.0f) + 1e-5f);
    #pragma unroll
    for (int j = 0; j < 8; ++j){
      const int c = lane + (j << 6);
      const float r = (x[j] - m) * inv * ln_g[c] + ln_b[c];
      const size_t o2 = gp * DIMV + c;
      if (WRITE_EMB) emb[o2] = f2bf(x[j]);
      lnout[o2] = f2bf(r);
    }
  }
}

// ---------------------------------------------------------------------------
// Tiled transpose: in [R][C] (fp32 or bf16) -> out bf16 [C][R]. 32x32 tiles.
// ---------------------------------------------------------------------------
template<typename TIN>
__global__ __launch_bounds__(256) void transp_kernel(
    const TIN* __restrict__ in, bfu* __restrict__ out, int R, int C,
    long long sIn, long long sOut)
{
  __shared__ bfu t[32][33];
  in  += (size_t)blockIdx.z * sIn;
  out += (size_t)blockIdx.z * sOut;
  const int c0 = blockIdx.x * 32, r0 = blockIdx.y * 32;
  const int tx = threadIdx.x & 31, ty = threadIdx.x >> 5;
  #pragma unroll
  for (int rr = ty; rr < 32; rr += 8)
    t[rr][tx] = to_bfu(in[(size_t)(r0 + rr) * C + c0 + tx]);
  __syncthreads();
  #pragma unroll
  for (int rr = ty; rr < 32; rr += 8)
    out[(size_t)(c0 + rr) * R + r0 + tx] = t[tx][rr];
}

// ---------------------------------------------------------------------------
// MFMA GEMM: C[M][N] = A[M][K] * B[N][K]^T, all bf16 inputs.
// 128x128 block tile, 4 waves (2x2), each wave 64x64 = 4x4 MFMA 16x16x32.
// LDS rows padded to 40 shorts (80 B = 20 banks -> 2-way max conflicts).
// ---------------------------------------------------------------------------
#define EPI_NONE     0
#define EPI_SPLIT    1
#define EPI_SCALE    2
#define EPI_BIAS_RES 3
#define LDST 40

template<typename TC, typename TR, int EPI>
__global__ __launch_bounds__(256, 2) void gemm_mfma(
    const bfu* __restrict__ A, const bfu* __restrict__ B,
    TC* __restrict__ C, TC* __restrict__ C2,
    const float* __restrict__ bias, const TR* __restrict__ res,
    float scale, int N, int K, int lda, int ldb, int ldc,
    long long sA, long long sB, long long sC)
{
  const int bz = blockIdx.z;
  A += (size_t)bz * sA;
  B += (size_t)bz * sB;
  const size_t coff = (size_t)bz * sC;

  __shared__ __align__(16) short As[128 * LDST];
  __shared__ __align__(16) short Bs[128 * LDST];

  const int tid = threadIdx.x;
  const int lane = tid & 63, w = tid >> 6;
  const int m0 = blockIdx.y * 128, n0 = blockIdx.x * 128;
  const int wm = (w & 1) * 64, wn = (w >> 1) * 64;
  const int fr = lane & 15, quad = lane >> 4;

  f32x4 acc[4][4];
  #pragma unroll
  for (int i = 0; i < 4; ++i)
    #pragma unroll
    for (int j = 0; j < 4; ++j)
      #pragma unroll
      for (int r = 0; r < 4; ++r) acc[i][j][r] = 0.f;

  for (int k0 = 0; k0 < K; k0 += 32){
    #pragma unroll
    for (int i = 0; i < 2; ++i){
      const int ch = tid + 256 * i;             // 512 16B-chunks per tile
      const int r = ch >> 2, c = ch & 3;
      *(uint4*)&As[r * LDST + c * 8] =
          *(const uint4*)(A + (size_t)(m0 + r) * lda + k0 + c * 8);
      *(uint4*)&Bs[r * LDST + c * 8] =
          *(const uint4*)(B + (size_t)(n0 + r) * ldb + k0 + c * 8);
    }
    __syncthreads();
    bf16x8 af[4], bf[4];
    #pragma unroll
    for (int i = 0; i < 4; ++i)
      af[i] = *(const bf16x8*)&As[(wm + i * 16 + fr) * LDST + quad * 8];
    #pragma unroll
    for (int j = 0; j < 4; ++j)
      bf[j] = *(const bf16x8*)&Bs[(wn + j * 16 + fr) * LDST + quad * 8];
    #pragma unroll
    for (int i = 0; i < 4; ++i)
      #pragma unroll
      for (int j = 0; j < 4; ++j)
        acc[i][j] = __builtin_amdgcn_mfma_f32_16x16x32_bf16(af[i], bf[j], acc[i][j], 0, 0, 0);
    __syncthreads();
  }

  // C/D layout: col = lane&15, row = quad*4 + reg
  TC* Cp = C + coff;
  #pragma unroll
  for (int i = 0; i < 4; ++i){
    #pragma unroll
    for (int r = 0; r < 4; ++r){
      const int cm = m0 + wm + i * 16 + quad * 4 + r;
      #pragma unroll
      for (int j = 0; j < 4; ++j){
        const int cn = n0 + wn + j * 16 + fr;
        float v = acc[i][j][r];
        if (EPI == EPI_SCALE)    v *= scale;
        if (EPI == EPI_BIAS_RES) v = v + bias[cn] + loadE(&res[coff + (size_t)cm * ldc + cn]);
        if (EPI == EPI_SPLIT){
          const int half = N >> 1;
          if (cn < half) storeE(&C [(size_t)cm * half + cn],          v);
          else           storeE(&C2[(size_t)cm * half + (cn - half)], v);
        } else {
          storeE(&Cp[(size_t)cm * ldc + cn], v);
        }
      }
    }
  }
}

// ---------------------------------------------------------------------------
// Fused MLP1 + exact GeLU (MFMA): act = (A@w1T[a]+b1a) * gelu(A@w1T[g]+b1g).
// Block tile: 128 rows x 128 act-cols; Ba/Bg are w1T rows n0.. and n0+2048..
// ---------------------------------------------------------------------------
__global__ __launch_bounds__(256, 1) void mlp1_mfma(
    const bfu* __restrict__ A, const bfu* __restrict__ B,  // B = w1T [4096][512]
    const float* __restrict__ b1, bfu* __restrict__ act)
{
  __shared__ __align__(16) short As[128 * LDST];
  __shared__ __align__(16) short Ba[128 * LDST];
  __shared__ __align__(16) short Bg[128 * LDST];

  const int tid = threadIdx.x;
  const int lane = tid & 63, w = tid >> 6;
  const int m0 = blockIdx.y * 128, n0 = blockIdx.x * 128;
  const int wm = (w & 1) * 64, wn = (w >> 1) * 64;
  const int fr = lane & 15, quad = lane >> 4;

  f32x4 acca[4][4], accg[4][4];
  #pragma unroll
  for (int i = 0; i < 4; ++i)
    #pragma unroll
    for (int j = 0; j < 4; ++j)
      #pragma unroll
      for (int r = 0; r < 4; ++r){ acca[i][j][r] = 0.f; accg[i][j][r] = 0.f; }

  for (int k0 = 0; k0 < 512; k0 += 32){
    #pragma unroll
    for (int i = 0; i < 2; ++i){
      const int ch = tid + 256 * i;
      const int r = ch >> 2, c = ch & 3;
      *(uint4*)&As[r * LDST + c * 8] =
          *(const uint4*)(A + (size_t)(m0 + r) * 512 + k0 + c * 8);
      *(uint4*)&Ba[r * LDST + c * 8] =
          *(const uint4*)(B + (size_t)(n0 + r) * 512 + k0 + c * 8);
      *(uint4*)&Bg[r * LDST + c * 8] =
          *(const uint4*)(B + (size_t)(n0 + 2048 + r) * 512 + k0 + c * 8);
    }
    __syncthreads();
    bf16x8 af[4], ba[4], bg[4];
    #pragma unroll
    for (int i = 0; i < 4; ++i)
      af[i] = *(const bf16x8*)&As[(wm + i * 16 + fr) * LDST + quad * 8];
    #pragma unroll
    for (int j = 0; j < 4; ++j){
      ba[j] = *(const bf16x8*)&Ba[(wn + j * 16 + fr) * LDST + quad * 8];
      bg[j] = *(const bf16x8*)&Bg[(wn + j * 16 + fr) * LDST + quad * 8];
    }
    #pragma unroll
    for (int i = 0; i < 4; ++i)
      #pragma unroll
      for (int j = 0; j < 4; ++j){
        acca[i][j] = __builtin_amdgcn_mfma_f32_16x16x32_bf16(af[i], ba[j], acca[i][j], 0, 0, 0);
        accg[i][j] = __builtin_amdgcn_mfma_f32_16x16x32_bf16(af[i], bg[j], accg[i][j], 0, 0, 0);
      }
    __syncthreads();
  }

  #pragma unroll
  for (int i = 0; i < 4; ++i){
    #pragma unroll
    for (int r = 0; r < 4; ++r){
      const int cm = m0 + wm + i * 16 + quad * 4 + r;
      #pragma unroll
      for (int j = 0; j < 4; ++j){
        const int cn = n0 + wn + j * 16 + fr;
        const float a = acca[i][j][r] + b1[cn];
        const float g = accg[i][j][r] + b1[cn + 2048];
        const float ge = g * 0.5f * (1.0f + erff(g * 0.70710678118654752f));
        act[(size_t)cm * 2048 + cn] = f2bf(a * ge);
      }
    }
  }
}

// ---------------------------------------------------------------------------
// Row softmax over 2048 bf16 logits, in place.
// ---------------------------------------------------------------------------
__global__ __launch_bounds__(256) void softmax_kernel(bfu* __restrict__ sc){
  __shared__ float red[4];
  const int tid = threadIdx.x;
  const int lane = tid & 63, wv = tid >> 6;
  bfu* rp = sc + (size_t)blockIdx.x * NCTX;
  float x[8];
  #pragma unroll
  for (int j = 0; j < 8; ++j) x[j] = bf2f(rp[tid + (j << 8)]);
  float mx = x[0];
  #pragma unroll
  for (int j = 1; j < 8; ++j) mx = fmaxf(mx, x[j]);
  for (int o = 32; o; o >>= 1) mx = fmaxf(mx, __shfl_xor(mx, o, 64));
  if (lane == 0) red[wv] = mx;
  __syncthreads();
  mx = fmaxf(fmaxf(red[0], red[1]), fmaxf(red[2], red[3]));
  float sum = 0.f;
  #pragma unroll
  for (int j = 0; j < 8; ++j){ x[j] = __expf(x[j] - mx); sum += x[j]; }
  for (int o = 32; o; o >>= 1) sum += __shfl_xor(sum, o, 64);
  __syncthreads();
  if (lane == 0) red[wv] = sum;
  __syncthreads();
  sum = red[0] + red[1] + red[2] + red[3];
  const float inv = 1.0f / sum;
  #pragma unroll
  for (int j = 0; j < 8; ++j) rp[tid + (j << 8)] = f2bf(x[j] * inv);
}

// ---------------------------------------------------------------------------
// LayerNorm rows of 512 fp32 -> bf16.
// ---------------------------------------------------------------------------
__global__ __launch_bounds__(256) void ln_kernel(const float* __restrict__ in,
                                                 const float* __restrict__ g,
                                                 const float* __restrict__ b,
                                                 bfu* __restrict__ out){
  const int tid = threadIdx.x, lane = tid & 63, wv = tid >> 6;
  const size_t row = (size_t)blockIdx.x * 4 + wv;
  const float* rp = in + row * DIMV;
  float x[8];
  #pragma unroll
  for (int j = 0; j < 8; ++j) x[j] = rp[lane + (j << 6)];
  float s = 0.f;
  #pragma unroll
  for (int j = 0; j < 8; ++j) s += x[j];
  for (int o = 32; o; o >>= 1) s += __shfl_xor(s, o, 64);
  const float m = s * (1.0f / 512.0f);
  float s2 = 0.f;
  #pragma unroll
  for (int j = 0; j < 8; ++j){ const float d = x[j] - m; s2 = fmaf(d, d, s2); }
  for (int o = 32; o; o >>= 1) s2 += __shfl_xor(s2, o, 64);
  const float inv = 1.0f / sqrtf(s2 * (1.0f / 512.0f) + 1e-5f);
  bfu* op = out + row * DIMV;
  #pragma unroll
  for (int j = 0; j < 8; ++j){
    const int c = lane + (j << 6);
    op[c] = f2bf((x[j] - m) * inv * g[c] + b[c]);
  }
}

// ---------------------------------------------------------------------------
// Workspace (peak 117,473,280 B < proven 125.8 MB):
//   idx    @ 0          (32 KB)
//   emb_s  @ 32768      (25,165,824) \  act half (50,331,648) aliases
//   q_in   @ 25198592   (25,165,824) /  emb_s+q_in after wo GEMM
//   c_grp  @ 50364416   (8,388,608)  -> scores
//   k_grp  @ 58753024   (8,388,608)
//   v_grp  @ 67141632   (8,388,608)
//   vT     @ 75530240   (8,388,608)
//   qbuf   @ 83918848   (25,165,824) -> lnx
//   wT     @ 109084672  (8,388,608): wqT|wkvT|woT|w1T|w2T
// ---------------------------------------------------------------------------
extern "C" void kernel_launch(void* const* d_in, const int* in_sizes, int n_in,
                              void* d_out, int out_size, void* d_ws, size_t ws_size,
                              hipStream_t stream)
{
  (void)in_sizes; (void)n_in; (void)out_size;
  if (ws_size < 117473280ull) return;

  const float* pc    = (const float*)d_in[0];
  const float* pc2   = (const float*)d_in[1];
  const float* basis = (const float*)d_in[2];
  const float* pe_w  = (const float*)d_in[3];
  const float* pe_b  = (const float*)d_in[4];
  const float* lnq_g = (const float*)d_in[5];
  const float* lnq_b = (const float*)d_in[6];
  const float* lnc_g = (const float*)d_in[7];
  const float* lnc_b = (const float*)d_in[8];
  const float* wq    = (const float*)d_in[9];
  const float* wkv   = (const float*)d_in[10];
  const float* wo    = (const float*)d_in[11];
  const float* bo    = (const float*)d_in[12];
  const float* lnf_g = (const float*)d_in[13];
  const float* lnf_b = (const float*)d_in[14];
  const float* w1    = (const float*)d_in[15];
  const float* b1    = (const float*)d_in[16];
  const float* w2    = (const float*)d_in[17];
  const float* b2    = (const float*)d_in[18];
  float* xout = (float*)d_out;

  char* ws = (char*)d_ws;
  int* idxb   = (int*)(ws);
  bfu* emb_s  = (bfu*)(ws + 32768);
  bfu* q_in   = (bfu*)(ws + 25198592);
  bfu* c_grp  = (bfu*)(ws + 50364416);
  bfu* k_grp  = (bfu*)(ws + 58753024);
  bfu* v_grp  = (bfu*)(ws + 67141632);
  bfu* vT     = (bfu*)(ws + 75530240);
  bfu* qbuf   = (bfu*)(ws + 83918848);
  bfu* wqT    = (bfu*)(ws + 109084672);
  bfu* wkvT   = (bfu*)(ws + 109608960);
  bfu* woT    = (bfu*)(ws + 110657536);
  bfu* w1T    = (bfu*)(ws + 111181824);
  bfu* w2T    = (bfu*)(ws + 115376128);
  bfu* scores  = c_grp;
  bfu* attnout = q_in;
  bfu* lnx     = qbuf;
  bfu* actb    = emb_s;     // spans emb_s+q_in (one MLP half at a time)

  // 0. weight transposes (fp32 [K][N] -> bf16 [N][K])
  transp_kernel<float><<<dim3(16, 16, 1),  256, 0, stream>>>(wq,  wqT,  512,  512, 0, 0);
  transp_kernel<float><<<dim3(32, 16, 1),  256, 0, stream>>>(wkv, wkvT, 512, 1024, 0, 0);
  transp_kernel<float><<<dim3(16, 16, 1),  256, 0, stream>>>(wo,  woT,  512,  512, 0, 0);
  transp_kernel<float><<<dim3(128, 16, 1), 256, 0, stream>>>(w1,  w1T,  512, 4096, 0, 0);
  transp_kernel<float><<<dim3(16, 64, 1),  256, 0, stream>>>(w2,  w2T, 2048,  512, 0, 0);

  // 1. FPS
  fps_kernel<<<NB, 256, 0, stream>>>(pc, idxb);

  // 2. latent embed -> emb_s (raw) + q_in (LN'd)
  embed_kernel<true, true><<<MROWS/16, 256, 0, stream>>>(
      pc, pc2, idxb, basis, pe_w, pe_b, lnq_g, lnq_b, emb_s, q_in, NLAT);

  // 3. q = q_in @ wq
  gemm_mfma<bfu, float, EPI_NONE><<<dim3(4, 192, 1), 256, 0, stream>>>(
      q_in, wqT, qbuf, nullptr, nullptr, nullptr, 1.0f,
      512, 512, 512, 512, 512, 0, 0, 0);

  // 4. per-group context pipeline
  for (int g = 0; g < NGRP; ++g){
    const int bt0 = g * GRP;
    embed_kernel<false, false><<<GROWS/16, 256, 0, stream>>>(
        pc + (size_t)bt0 * NCTX * 3, pc2 + (size_t)bt0 * NCTX * 3, nullptr,
        basis, pe_w, pe_b, lnc_g, lnc_b, nullptr, c_grp, NCTX);

    gemm_mfma<bfu, float, EPI_SPLIT><<<dim3(8, 64, 1), 256, 0, stream>>>(
        c_grp, wkvT, k_grp, v_grp, nullptr, nullptr, 1.0f,
        1024, 512, 512, 512, 512, 0, 0, 0);

    transp_kernel<bfu><<<dim3(16, 64, GRP), 256, 0, stream>>>(
        v_grp, vT, 2048, 512, 2048*512, 2048*512);

    // scores = (q @ k^T) * scale, bf16 (overwrites c_grp)
    gemm_mfma<bfu, float, EPI_SCALE><<<dim3(16, 4, GRP), 256, 0, stream>>>(
        qbuf + (size_t)bt0 * 262144, k_grp, scores, nullptr, nullptr, nullptr,
        0.044194173824159216f,
        2048, 512, 512, 512, 2048, 262144, 1048576, 1048576);

    softmax_kernel<<<GRP * 512, 256, 0, stream>>>(scores);

    // attnout = P @ V  (B = vT, [512][2048])
    gemm_mfma<bfu, float, EPI_NONE><<<dim3(4, 4, GRP), 256, 0, stream>>>(
        scores, vT, attnout + (size_t)bt0 * 262144, nullptr, nullptr, nullptr, 1.0f,
        512, 2048, 2048, 2048, 512, 1048576, 1048576, 262144);
  }

  // 5. x = attnout @ wo + bo + emb_s -> d_out (fp32)
  gemm_mfma<float, bfu, EPI_BIAS_RES><<<dim3(4, 192, 1), 256, 0, stream>>>(
      attnout, woT, xout, nullptr, bo, emb_s, 1.0f,
      512, 512, 512, 512, 512, 0, 0, 0);

  // 6. lnx = LN(x)
  ln_kernel<<<MROWS/4, 256, 0, stream>>>(xout, lnf_g, lnf_b, lnx);

  // 7/8. MLP in two row-halves (act buffer holds one half)
  for (int h = 0; h < 2; ++h){
    const size_t ro = (size_t)h * 12288;
    mlp1_mfma<<<dim3(16, 96, 1), 256, 0, stream>>>(
        lnx + ro * 512, w1T, b1, actb);
    gemm_mfma<float, float, EPI_BIAS_RES><<<dim3(4, 96, 1), 256, 0, stream>>>(
        actb, w2T, xout + ro * 512, nullptr, b2, xout + ro * 512, 1.0f,
        512, 2048, 2048, 2048, 512, 0, 0, 0);
  }
}

// Round 4
// 2598.866 us; speedup vs baseline: 4.5274x; 1.1196x over previous
//
#include <hip/hip_runtime.h>

// Problem constants
#define NB    16
#define NT    3
#define NCTX  2048
#define NLAT  512
#define DIMV  512
#define HALFD 256
#define NFEAT 51
#define NBT   48
#define MROWS 24576    // NBT*NLAT
#define GRP   4        // bt per context group
#define NGRP  12
#define GROWS 8192     // GRP*NCTX

typedef unsigned short bfu;   // bf16 storage as raw bits
typedef short bf16x8 __attribute__((ext_vector_type(8)));   // 8 bf16 = 4 VGPR
typedef float f32x4  __attribute__((ext_vector_type(4)));   // MFMA 16x16 acc

__device__ __forceinline__ float bf2f(bfu u){ return __uint_as_float(((unsigned int)u) << 16); }
__device__ __forceinline__ bfu f2bf(float f){
  unsigned int u = __float_as_uint(f);
  u += 0x7FFFu + ((u >> 16) & 1u);          // RNE
  return (bfu)(u >> 16);
}
__device__ __forceinline__ float loadE(const float* p){ return *p; }
__device__ __forceinline__ float loadE(const bfu* p){ return bf2f(*p); }
__device__ __forceinline__ void storeE(float* p, float v){ *p = v; }
__device__ __forceinline__ void storeE(bfu* p, float v){ *p = f2bf(v); }
__device__ __forceinline__ bfu to_bfu(float f){ return f2bf(f); }
__device__ __forceinline__ bfu to_bfu(bfu u){ return u; }

// ---------------------------------------------------------------------------
// FPS, wave-synchronous: one 64-lane wave per batch, no barriers in the loop.
// Coords + dist in VGPRs (32 pts/lane); LDS coord copy for the broadcast read
// of pts[last]. Bit-exact fp32 (no FMA contraction, numpy sum order,
// first-occurrence argmax via strict-> local scan + min-index tie-break).
// ---------------------------------------------------------------------------
__global__ __launch_bounds__(64) void fps_kernel(const float* __restrict__ pc,
                                                 int* __restrict__ idx_out){
  __shared__ float cx[NCTX], cy[NCTX], cz[NCTX];
  const int b = blockIdx.x, lane = threadIdx.x;
  const float* src = pc + (size_t)b * (NT * NCTX * 3);

  float px[32], py[32], pz[32], dist[32];
  #pragma unroll
  for (int j = 0; j < 32; ++j){
    const int i = lane + (j << 6);
    const float x = src[i*3+0], y = src[i*3+1], z = src[i*3+2];
    px[j] = x; py[j] = y; pz[j] = z; dist[j] = 1e10f;
    cx[i] = x; cy[i] = y; cz[i] = z;
  }
  if (lane == 0) idx_out[b * NLAT] = 0;
  __syncthreads();   // one-time: LDS coords visible (single wave, cheap)

  int last = 0;
  for (int step = 1; step < NLAT; ++step){
    const float lx = cx[last], ly = cy[last], lz = cz[last];  // broadcast read
    float bv = -1.0f; int bi = 0;
    #pragma unroll
    for (int j = 0; j < 32; ++j){
      const float dx = __fsub_rn(px[j], lx);
      const float dy = __fsub_rn(py[j], ly);
      const float dz = __fsub_rn(pz[j], lz);
      const float d  = __fadd_rn(__fadd_rn(__fmul_rn(dx,dx), __fmul_rn(dy,dy)),
                                 __fmul_rn(dz,dz));
      const float nd = fminf(dist[j], d);
      dist[j] = nd;
      if (nd > bv){ bv = nd; bi = lane + (j << 6); }   // ascending global idx
    }
    #pragma unroll
    for (int off = 1; off < 64; off <<= 1){
      const float ov = __shfl_xor(bv, off, 64);
      const int   oi = __shfl_xor(bi, off, 64);
      if (ov > bv || (ov == bv && oi < bi)){ bv = ov; bi = oi; }
    }
    last = bi;                       // every lane holds the argmax
    if (lane == 0) idx_out[b * NLAT + step] = bi;
  }
}

// ---------------------------------------------------------------------------
// Fused (gather) + point_embed x2 + layernorm -> bf16. 16 points / block.
// ---------------------------------------------------------------------------
template<bool GATHER, bool WRITE_EMB>
__global__ __launch_bounds__(256) void embed_kernel(
    const float* __restrict__ pc, const float* __restrict__ pc2,
    const int* __restrict__ idx,
    const float* __restrict__ basis, const float* __restrict__ pe_w,
    const float* __restrict__ pe_b,
    const float* __restrict__ ln_g, const float* __restrict__ ln_b,
    bfu* __restrict__ emb, bfu* __restrict__ lnout, int nppbt)
{
  __shared__ float feat[2][16][NFEAT + 1];
  __shared__ float outb[16][DIMV];
  const int tid = threadIdx.x;
  const int p0 = blockIdx.x << 4;

  if (tid < 32){
    const int s = tid >> 4, p = tid & 15;
    const int gp = p0 + p;
    const int bt = gp / nppbt;
    const int n  = gp - bt * nppbt;
    const int bb = bt / NT;
    const int srcn = GATHER ? idx[bb * NLAT + n] : n;
    const float* sp = (s ? pc2 : pc) + ((size_t)bt * NCTX + srcn) * 3;
    const float x0 = sp[0], x1 = sp[1], x2 = sp[2];
    #pragma unroll
    for (int e = 0; e < 24; ++e){
      const float pr = __fadd_rn(__fadd_rn(__fmul_rn(x0, basis[e]),
                                           __fmul_rn(x1, basis[24 + e])),
                                 __fmul_rn(x2, basis[48 + e]));
      feat[s][p][e]      = sinf(pr);
      feat[s][p][24 + e] = cosf(pr);
    }
    feat[s][p][48] = x0; feat[s][p][49] = x1; feat[s][p][50] = x2;
  }
  __syncthreads();

  {
    float w[NFEAT];
    #pragma unroll
    for (int k = 0; k < NFEAT; ++k) w[k] = pe_w[k * HALFD + tid];
    const float bv = pe_b[tid];
    #pragma unroll
    for (int half = 0; half < 2; ++half){
      for (int p = 0; p < 16; ++p){
        float acc = bv;
        #pragma unroll
        for (int k = 0; k < NFEAT; ++k) acc = fmaf(feat[half][p][k], w[k], acc);
        outb[p][half * HALFD + tid] = acc;
      }
    }
  }
  __syncthreads();

  const int lane = tid & 63, wv = tid >> 6;
  for (int pp = 0; pp < 4; ++pp){
    const int p = (wv << 2) + pp;
    const size_t gp = (size_t)p0 + p;
    float x[8];
    #pragma unroll
    for (int j = 0; j < 8; ++j) x[j] = outb[p][lane + (j << 6)];
    float s = 0.f;
    #pragma unroll
    for (int j = 0; j < 8; ++j) s += x[j];
    for (int o = 32; o; o >>= 1) s += __shfl_xor(s, o, 64);
    const float m = s * (1.0f / 512.0f);
    float s2 = 0.f;
    #pragma unroll
    for (int j = 0; j < 8; ++j){ const float d = x[j] - m; s2 = fmaf(d, d, s2); }
    for (int o = 32; o; o >>= 1) s2 += __shfl_xor(s2, o, 64);
    const float inv = 1.0f / sqrtf(s2 * (1.0f / 512.0f) + 1e-5f);
    #pragma unroll
    for (int j = 0; j < 8; ++j){
      const int c = lane + (j << 6);
      const float r = (x[j] - m) * inv * ln_g[c] + ln_b[c];
      const size_t o2 = gp * DIMV + c;
      if (WRITE_EMB) emb[o2] = f2bf(x[j]);
      lnout[o2] = f2bf(r);
    }
  }
}

// ---------------------------------------------------------------------------
// Tiled transpose: in [R][C] (fp32 or bf16) -> out bf16 [C][R]. 32x32 tiles.
// ---------------------------------------------------------------------------
template<typename TIN>
__global__ __launch_bounds__(256) void transp_kernel(
    const TIN* __restrict__ in, bfu* __restrict__ out, int R, int C,
    long long sIn, long long sOut)
{
  __shared__ bfu t[32][33];
  in  += (size_t)blockIdx.z * sIn;
  out += (size_t)blockIdx.z * sOut;
  const int c0 = blockIdx.x * 32, r0 = blockIdx.y * 32;
  const int tx = threadIdx.x & 31, ty = threadIdx.x >> 5;
  #pragma unroll
  for (int rr = ty; rr < 32; rr += 8)
    t[rr][tx] = to_bfu(in[(size_t)(r0 + rr) * C + c0 + tx]);
  __syncthreads();
  #pragma unroll
  for (int rr = ty; rr < 32; rr += 8)
    out[(size_t)(c0 + rr) * R + r0 + tx] = t[tx][rr];
}

// ---------------------------------------------------------------------------
// MFMA GEMM: C[M][N] = A[M][K] * B[N][K]^T, all bf16 inputs.
// 128x128 block tile, 4 waves (2x2), each wave 64x64 = 4x4 MFMA 16x16x32.
// LDS rows padded to 40 shorts (80 B = 20 banks -> 2-way max conflicts).
// ---------------------------------------------------------------------------
#define EPI_NONE     0
#define EPI_SPLIT    1
#define EPI_SCALE    2
#define EPI_BIAS_RES 3
#define LDST 40

template<typename TC, typename TR, int EPI>
__global__ __launch_bounds__(256, 2) void gemm_mfma(
    const bfu* __restrict__ A, const bfu* __restrict__ B,
    TC* __restrict__ C, TC* __restrict__ C2,
    const float* __restrict__ bias, const TR* __restrict__ res,
    float scale, int N, int K, int lda, int ldb, int ldc,
    long long sA, long long sB, long long sC)
{
  const int bz = blockIdx.z;
  A += (size_t)bz * sA;
  B += (size_t)bz * sB;
  const size_t coff = (size_t)bz * sC;

  __shared__ __align__(16) short As[128 * LDST];
  __shared__ __align__(16) short Bs[128 * LDST];

  const int tid = threadIdx.x;
  const int lane = tid & 63, w = tid >> 6;
  const int m0 = blockIdx.y * 128, n0 = blockIdx.x * 128;
  const int wm = (w & 1) * 64, wn = (w >> 1) * 64;
  const int fr = lane & 15, quad = lane >> 4;

  f32x4 acc[4][4];
  #pragma unroll
  for (int i = 0; i < 4; ++i)
    #pragma unroll
    for (int j = 0; j < 4; ++j)
      #pragma unroll
      for (int r = 0; r < 4; ++r) acc[i][j][r] = 0.f;

  for (int k0 = 0; k0 < K; k0 += 32){
    #pragma unroll
    for (int i = 0; i < 2; ++i){
      const int ch = tid + 256 * i;             // 512 16B-chunks per tile
      const int r = ch >> 2, c = ch & 3;
      *(uint4*)&As[r * LDST + c * 8] =
          *(const uint4*)(A + (size_t)(m0 + r) * lda + k0 + c * 8);
      *(uint4*)&Bs[r * LDST + c * 8] =
          *(const uint4*)(B + (size_t)(n0 + r) * ldb + k0 + c * 8);
    }
    __syncthreads();
    bf16x8 af[4], bf[4];
    #pragma unroll
    for (int i = 0; i < 4; ++i)
      af[i] = *(const bf16x8*)&As[(wm + i * 16 + fr) * LDST + quad * 8];
    #pragma unroll
    for (int j = 0; j < 4; ++j)
      bf[j] = *(const bf16x8*)&Bs[(wn + j * 16 + fr) * LDST + quad * 8];
    #pragma unroll
    for (int i = 0; i < 4; ++i)
      #pragma unroll
      for (int j = 0; j < 4; ++j)
        acc[i][j] = __builtin_amdgcn_mfma_f32_16x16x32_bf16(af[i], bf[j], acc[i][j], 0, 0, 0);
    __syncthreads();
  }

  // C/D layout: col = lane&15, row = quad*4 + reg
  TC* Cp = C + coff;
  #pragma unroll
  for (int i = 0; i < 4; ++i){
    #pragma unroll
    for (int r = 0; r < 4; ++r){
      const int cm = m0 + wm + i * 16 + quad * 4 + r;
      #pragma unroll
      for (int j = 0; j < 4; ++j){
        const int cn = n0 + wn + j * 16 + fr;
        float v = acc[i][j][r];
        if (EPI == EPI_SCALE)    v *= scale;
        if (EPI == EPI_BIAS_RES) v = v + bias[cn] + loadE(&res[coff + (size_t)cm * ldc + cn]);
        if (EPI == EPI_SPLIT){
          const int half = N >> 1;
          if (cn < half) storeE(&C [(size_t)cm * half + cn],          v);
          else           storeE(&C2[(size_t)cm * half + (cn - half)], v);
        } else {
          storeE(&Cp[(size_t)cm * ldc + cn], v);
        }
      }
    }
  }
}

// ---------------------------------------------------------------------------
// Fused MLP1 + exact GeLU (MFMA): act = (A@w1T[a]+b1a) * gelu(A@w1T[g]+b1g).
// ---------------------------------------------------------------------------
__global__ __launch_bounds__(256, 1) void mlp1_mfma(
    const bfu* __restrict__ A, const bfu* __restrict__ B,  // B = w1T [4096][512]
    const float* __restrict__ b1, bfu* __restrict__ act)
{
  __shared__ __align__(16) short As[128 * LDST];
  __shared__ __align__(16) short Ba[128 * LDST];
  __shared__ __align__(16) short Bg[128 * LDST];

  const int tid = threadIdx.x;
  const int lane = tid & 63, w = tid >> 6;
  const int m0 = blockIdx.y * 128, n0 = blockIdx.x * 128;
  const int wm = (w & 1) * 64, wn = (w >> 1) * 64;
  const int fr = lane & 15, quad = lane >> 4;

  f32x4 acca[4][4], accg[4][4];
  #pragma unroll
  for (int i = 0; i < 4; ++i)
    #pragma unroll
    for (int j = 0; j < 4; ++j)
      #pragma unroll
      for (int r = 0; r < 4; ++r){ acca[i][j][r] = 0.f; accg[i][j][r] = 0.f; }

  for (int k0 = 0; k0 < 512; k0 += 32){
    #pragma unroll
    for (int i = 0; i < 2; ++i){
      const int ch = tid + 256 * i;
      const int r = ch >> 2, c = ch & 3;
      *(uint4*)&As[r * LDST + c * 8] =
          *(const uint4*)(A + (size_t)(m0 + r) * 512 + k0 + c * 8);
      *(uint4*)&Ba[r * LDST + c * 8] =
          *(const uint4*)(B + (size_t)(n0 + r) * 512 + k0 + c * 8);
      *(uint4*)&Bg[r * LDST + c * 8] =
          *(const uint4*)(B + (size_t)(n0 + 2048 + r) * 512 + k0 + c * 8);
    }
    __syncthreads();
    bf16x8 af[4], ba[4], bg[4];
    #pragma unroll
    for (int i = 0; i < 4; ++i)
      af[i] = *(const bf16x8*)&As[(wm + i * 16 + fr) * LDST + quad * 8];
    #pragma unroll
    for (int j = 0; j < 4; ++j){
      ba[j] = *(const bf16x8*)&Ba[(wn + j * 16 + fr) * LDST + quad * 8];
      bg[j] = *(const bf16x8*)&Bg[(wn + j * 16 + fr) * LDST + quad * 8];
    }
    #pragma unroll
    for (int i = 0; i < 4; ++i)
      #pragma unroll
      for (int j = 0; j < 4; ++j){
        acca[i][j] = __builtin_amdgcn_mfma_f32_16x16x32_bf16(af[i], ba[j], acca[i][j], 0, 0, 0);
        accg[i][j] = __builtin_amdgcn_mfma_f32_16x16x32_bf16(af[i], bg[j], accg[i][j], 0, 0, 0);
      }
    __syncthreads();
  }

  #pragma unroll
  for (int i = 0; i < 4; ++i){
    #pragma unroll
    for (int r = 0; r < 4; ++r){
      const int cm = m0 + wm + i * 16 + quad * 4 + r;
      #pragma unroll
      for (int j = 0; j < 4; ++j){
        const int cn = n0 + wn + j * 16 + fr;
        const float a = acca[i][j][r] + b1[cn];
        const float g = accg[i][j][r] + b1[cn + 2048];
        const float ge = g * 0.5f * (1.0f + erff(g * 0.70710678118654752f));
        act[(size_t)cm * 2048 + cn] = f2bf(a * ge);
      }
    }
  }
}

// ---------------------------------------------------------------------------
// Row softmax over 2048 bf16 logits, in place.
// ---------------------------------------------------------------------------
__global__ __launch_bounds__(256) void softmax_kernel(bfu* __restrict__ sc){
  __shared__ float red[4];
  const int tid = threadIdx.x;
  const int lane = tid & 63, wv = tid >> 6;
  bfu* rp = sc + (size_t)blockIdx.x * NCTX;
  float x[8];
  #pragma unroll
  for (int j = 0; j < 8; ++j) x[j] = bf2f(rp[tid + (j << 8)]);
  float mx = x[0];
  #pragma unroll
  for (int j = 1; j < 8; ++j) mx = fmaxf(mx, x[j]);
  for (int o = 32; o; o >>= 1) mx = fmaxf(mx, __shfl_xor(mx, o, 64));
  if (lane == 0) red[wv] = mx;
  __syncthreads();
  mx = fmaxf(fmaxf(red[0], red[1]), fmaxf(red[2], red[3]));
  float sum = 0.f;
  #pragma unroll
  for (int j = 0; j < 8; ++j){ x[j] = __expf(x[j] - mx); sum += x[j]; }
  for (int o = 32; o; o >>= 1) sum += __shfl_xor(sum, o, 64);
  __syncthreads();
  if (lane == 0) red[wv] = sum;
  __syncthreads();
  sum = red[0] + red[1] + red[2] + red[3];
  const float inv = 1.0f / sum;
  #pragma unroll
  for (int j = 0; j < 8; ++j) rp[tid + (j << 8)] = f2bf(x[j] * inv);
}

// ---------------------------------------------------------------------------
// LayerNorm rows of 512 fp32 -> bf16.
// ---------------------------------------------------------------------------
__global__ __launch_bounds__(256) void ln_kernel(const float* __restrict__ in,
                                                 const float* __restrict__ g,
                                                 const float* __restrict__ b,
                                                 bfu* __restrict__ out){
  const int tid = threadIdx.x, lane = tid & 63, wv = tid >> 6;
  const size_t row = (size_t)blockIdx.x * 4 + wv;
  const float* rp = in + row * DIMV;
  float x[8];
  #pragma unroll
  for (int j = 0; j < 8; ++j) x[j] = rp[lane + (j << 6)];
  float s = 0.f;
  #pragma unroll
  for (int j = 0; j < 8; ++j) s += x[j];
  for (int o = 32; o; o >>= 1) s += __shfl_xor(s, o, 64);
  const float m = s * (1.0f / 512.0f);
  float s2 = 0.f;
  #pragma unroll
  for (int j = 0; j < 8; ++j){ const float d = x[j] - m; s2 = fmaf(d, d, s2); }
  for (int o = 32; o; o >>= 1) s2 += __shfl_xor(s2, o, 64);
  const float inv = 1.0f / sqrtf(s2 * (1.0f / 512.0f) + 1e-5f);
  bfu* op = out + row * DIMV;
  #pragma unroll
  for (int j = 0; j < 8; ++j){
    const int c = lane + (j << 6);
    op[c] = f2bf((x[j] - m) * inv * g[c] + b[c]);
  }
}

// ---------------------------------------------------------------------------
// Workspace (peak 117,473,280 B < proven 125.8 MB):
//   idx    @ 0          (32 KB)
//   emb_s  @ 32768      (25,165,824) \  act half (50,331,648) aliases
//   q_in   @ 25198592   (25,165,824) /  emb_s+q_in after wo GEMM
//   c_grp  @ 50364416   (8,388,608)  -> scores
//   k_grp  @ 58753024   (8,388,608)
//   v_grp  @ 67141632   (8,388,608)
//   vT     @ 75530240   (8,388,608)
//   qbuf   @ 83918848   (25,165,824) -> lnx
//   wT     @ 109084672  (8,388,608): wqT|wkvT|woT|w1T|w2T
// ---------------------------------------------------------------------------
extern "C" void kernel_launch(void* const* d_in, const int* in_sizes, int n_in,
                              void* d_out, int out_size, void* d_ws, size_t ws_size,
                              hipStream_t stream)
{
  (void)in_sizes; (void)n_in; (void)out_size;
  if (ws_size < 117473280ull) return;

  const float* pc    = (const float*)d_in[0];
  const float* pc2   = (const float*)d_in[1];
  const float* basis = (const float*)d_in[2];
  const float* pe_w  = (const float*)d_in[3];
  const float* pe_b  = (const float*)d_in[4];
  const float* lnq_g = (const float*)d_in[5];
  const float* lnq_b = (const float*)d_in[6];
  const float* lnc_g = (const float*)d_in[7];
  const float* lnc_b = (const float*)d_in[8];
  const float* wq    = (const float*)d_in[9];
  const float* wkv   = (const float*)d_in[10];
  const float* wo    = (const float*)d_in[11];
  const float* bo    = (const float*)d_in[12];
  const float* lnf_g = (const float*)d_in[13];
  const float* lnf_b = (const float*)d_in[14];
  const float* w1    = (const float*)d_in[15];
  const float* b1    = (const float*)d_in[16];
  const float* w2    = (const float*)d_in[17];
  const float* b2    = (const float*)d_in[18];
  float* xout = (float*)d_out;

  char* ws = (char*)d_ws;
  int* idxb   = (int*)(ws);
  bfu* emb_s  = (bfu*)(ws + 32768);
  bfu* q_in   = (bfu*)(ws + 25198592);
  bfu* c_grp  = (bfu*)(ws + 50364416);
  bfu* k_grp  = (bfu*)(ws + 58753024);
  bfu* v_grp  = (bfu*)(ws + 67141632);
  bfu* vT     = (bfu*)(ws + 75530240);
  bfu* qbuf   = (bfu*)(ws + 83918848);
  bfu* wqT    = (bfu*)(ws + 109084672);
  bfu* wkvT   = (bfu*)(ws + 109608960);
  bfu* woT    = (bfu*)(ws + 110657536);
  bfu* w1T    = (bfu*)(ws + 111181824);
  bfu* w2T    = (bfu*)(ws + 115376128);
  bfu* scores  = c_grp;
  bfu* attnout = q_in;
  bfu* lnx     = qbuf;
  bfu* actb    = emb_s;     // spans emb_s+q_in (one MLP half at a time)

  // 0. weight transposes (fp32 [K][N] -> bf16 [N][K])
  transp_kernel<float><<<dim3(16, 16, 1),  256, 0, stream>>>(wq,  wqT,  512,  512, 0, 0);
  transp_kernel<float><<<dim3(32, 16, 1),  256, 0, stream>>>(wkv, wkvT, 512, 1024, 0, 0);
  transp_kernel<float><<<dim3(16, 16, 1),  256, 0, stream>>>(wo,  woT,  512,  512, 0, 0);
  transp_kernel<float><<<dim3(128, 16, 1), 256, 0, stream>>>(w1,  w1T,  512, 4096, 0, 0);
  transp_kernel<float><<<dim3(16, 64, 1),  256, 0, stream>>>(w2,  w2T, 2048,  512, 0, 0);

  // 1. FPS (wave-synchronous, one wave per batch)
  fps_kernel<<<NB, 64, 0, stream>>>(pc, idxb);

  // 2. latent embed -> emb_s (raw) + q_in (LN'd)
  embed_kernel<true, true><<<MROWS/16, 256, 0, stream>>>(
      pc, pc2, idxb, basis, pe_w, pe_b, lnq_g, lnq_b, emb_s, q_in, NLAT);

  // 3. q = q_in @ wq
  gemm_mfma<bfu, float, EPI_NONE><<<dim3(4, 192, 1), 256, 0, stream>>>(
      q_in, wqT, qbuf, nullptr, nullptr, nullptr, 1.0f,
      512, 512, 512, 512, 512, 0, 0, 0);

  // 4. per-group context pipeline
  for (int g = 0; g < NGRP; ++g){
    const int bt0 = g * GRP;
    embed_kernel<false, false><<<GROWS/16, 256, 0, stream>>>(
        pc + (size_t)bt0 * NCTX * 3, pc2 + (size_t)bt0 * NCTX * 3, nullptr,
        basis, pe_w, pe_b, lnc_g, lnc_b, nullptr, c_grp, NCTX);

    gemm_mfma<bfu, float, EPI_SPLIT><<<dim3(8, 64, 1), 256, 0, stream>>>(
        c_grp, wkvT, k_grp, v_grp, nullptr, nullptr, 1.0f,
        1024, 512, 512, 512, 512, 0, 0, 0);

    transp_kernel<bfu><<<dim3(16, 64, GRP), 256, 0, stream>>>(
        v_grp, vT, 2048, 512, 2048*512, 2048*512);

    // scores = (q @ k^T) * scale, bf16 (overwrites c_grp)
    gemm_mfma<bfu, float, EPI_SCALE><<<dim3(16, 4, GRP), 256, 0, stream>>>(
        qbuf + (size_t)bt0 * 262144, k_grp, scores, nullptr, nullptr, nullptr,
        0.044194173824159216f,
        2048, 512, 512, 512, 2048, 262144, 1048576, 1048576);

    softmax_kernel<<<GRP * 512, 256, 0, stream>>>(scores);

    // attnout = P @ V  (B = vT, [512][2048])
    gemm_mfma<bfu, float, EPI_NONE><<<dim3(4, 4, GRP), 256, 0, stream>>>(
        scores, vT, attnout + (size_t)bt0 * 262144, nullptr, nullptr, nullptr, 1.0f,
        512, 2048, 2048, 2048, 512, 1048576, 1048576, 262144);
  }

  // 5. x = attnout @ wo + bo + emb_s -> d_out (fp32)
  gemm_mfma<float, bfu, EPI_BIAS_RES><<<dim3(4, 192, 1), 256, 0, stream>>>(
      attnout, woT, xout, nullptr, bo, emb_s, 1.0f,
      512, 512, 512, 512, 512, 0, 0, 0);

  // 6. lnx = LN(x)
  ln_kernel<<<MROWS/4, 256, 0, stream>>>(xout, lnf_g, lnf_b, lnx);

  // 7/8. MLP in two row-halves (act buffer holds one half)
  for (int h = 0; h < 2; ++h){
    const size_t ro = (size_t)h * 12288;
    mlp1_mfma<<<dim3(16, 96, 1), 256, 0, stream>>>(
        lnx + ro * 512, w1T, b1, actb);
    gemm_mfma<float, float, EPI_BIAS_RES><<<dim3(4, 96, 1), 256, 0, stream>>>(
        actb, w2T, xout + ro * 512, nullptr, b2, xout + ro * 512, 1.0f,
        512, 2048, 2048, 2048, 512, 0, 0, 0);
  }
}